// Round 6
// baseline (442.217 us; speedup 1.0000x reference)
//
#include <hip/hip_runtime.h>

#define D 64

// --- degree histogram over dst (4 edges/thread, int4 loads) ----------------
__global__ void count_deg_kernel(const int* __restrict__ dst, int* __restrict__ deg, int nE) {
    int e4 = (blockIdx.x * blockDim.x + threadIdx.x) * 4;
    if (e4 + 3 < nE) {
        int4 d = *(const int4*)(dst + e4);
        atomicAdd(&deg[d.x], 1);
        atomicAdd(&deg[d.y], 1);
        atomicAdd(&deg[d.z], 1);
        atomicAdd(&deg[d.w], 1);
    } else {
        for (int e = e4; e < nE; ++e) atomicAdd(&deg[dst[e]], 1);
    }
}

// --- hierarchical exclusive scan: A (per-block tile scan) ------------------
__global__ __launch_bounds__(256) void scan_a_kernel(const int* __restrict__ deg,
                                                     int* __restrict__ row_ptr,
                                                     int* __restrict__ blocksums, int N) {
    __shared__ int s[256];
    int t = threadIdx.x;
    int i = blockIdx.x * 256 + t;
    int v = (i < N) ? deg[i] : 0;
    s[t] = v;
    __syncthreads();
    #pragma unroll
    for (int d = 1; d < 256; d <<= 1) {
        int u = (t >= d) ? s[t - d] : 0;
        __syncthreads();
        s[t] += u;
        __syncthreads();
    }
    if (i < N) row_ptr[i] = s[t] - v;             // exclusive (block-local)
    if (t == 255) blocksums[blockIdx.x] = s[255]; // block total
}

// --- B: single-block exclusive scan of block sums (nb <= 256) --------------
__global__ __launch_bounds__(256) void scan_b_kernel(int* __restrict__ blocksums,
                                                     int* __restrict__ row_ptr,
                                                     int nb, int N) {
    __shared__ int s[256];
    int t = threadIdx.x;
    int v = (t < nb) ? blocksums[t] : 0;
    s[t] = v;
    __syncthreads();
    #pragma unroll
    for (int d = 1; d < 256; d <<= 1) {
        int u = (t >= d) ? s[t - d] : 0;
        __syncthreads();
        s[t] += u;
        __syncthreads();
    }
    if (t < nb) blocksums[t] = s[t] - v;  // exclusive block offsets
    if (t == 255) row_ptr[N] = s[255];    // total = E
}

// --- C: apply block offsets, emit final row_ptr + cursor -------------------
__global__ __launch_bounds__(256) void scan_c_kernel(int* __restrict__ row_ptr,
                                                     int* __restrict__ cursor,
                                                     const int* __restrict__ blocksums, int N) {
    int i = blockIdx.x * 256 + threadIdx.x;
    if (i < N) {
        int r = row_ptr[i] + blocksums[blockIdx.x];
        row_ptr[i] = r;
        cursor[i] = r;
    }
}

// --- bucket edges by dst: col[pos] = src, dst-sliced for XCD locality ------
__global__ __launch_bounds__(256) void fill_csr_sliced_kernel(
    const int* __restrict__ src, const int* __restrict__ dst,
    int* __restrict__ cursor, int* __restrict__ col,
    int nE, int slice_size)
{
    const int g  = blockIdx.x & 7;    // slice id == XCD id (perf heuristic)
    const int gb = blockIdx.x >> 3;   // block index within group
    const int lo = g * slice_size;
    const int hi = lo + slice_size;
    int e4 = (gb * 256 + (int)threadIdx.x) * 4;
    if (e4 + 3 < nE) {
        int4 d = *(const int4*)(dst + e4);
        bool m0 = (d.x >= lo) & (d.x < hi);
        bool m1 = (d.y >= lo) & (d.y < hi);
        bool m2 = (d.z >= lo) & (d.z < hi);
        bool m3 = (d.w >= lo) & (d.w < hi);
        if (m0 | m1 | m2 | m3) {
            int4 s = *(const int4*)(src + e4);
            if (m0) col[atomicAdd(&cursor[d.x], 1)] = s.x;
            if (m1) col[atomicAdd(&cursor[d.y], 1)] = s.y;
            if (m2) col[atomicAdd(&cursor[d.z], 1)] = s.z;
            if (m3) col[atomicAdd(&cursor[d.w], 1)] = s.w;
        }
    } else if (e4 < nE) {
        for (int e = e4; e < nE; ++e) {
            int dd = dst[e];
            if (dd >= lo && dd < hi) col[atomicAdd(&cursor[dd], 1)] = src[e];
        }
    }
}

// --- fused layer: out = relu?( ((sum_{s in N(i)} h[s] + h[i]) / (deg+1)) @ W + b )
// One wave per node, zero barriers in the node loop. Body = round-4 (proven
// clean: zero scratch, WRITE=12.5MB); slab machinery of round 5 deleted
// (FETCH unchanged at 80.7MB -> zero locality gain, 1.6x slower from
// compaction overhead + reduced gather MLP).
//
// ROUND 6: the occupancy A/B that rounds 0-5 never actually ran.
// Evidence: VGPR_Count excludes AGPRs (r0 showed 60 while Wreg[64] sat in
// AGPRs). r4's bounds(256,4) = 128-reg budget let the compiler expand into
// AGPR temporaries -> ~124 unified -> 4 blocks/CU -> occupancy 32%, same as
// r0 (hence identical 46us: same residency, same body — NOT an occupancy A/B).
// r1-r3's bounds(256,8) = 64-reg cap was below the ~70-reg live set -> the
// spiller demoted in-flight gather values to scratch (WRITE 205MB, 3x slower).
// bounds(256,6) = 85-reg budget: above the ~60-reg live set (no spill),
// below the AGPR-expansion regime -> 6 waves/EU, 24 waves/CU, clean code.
__global__ __launch_bounds__(256, 6) void sage_layer_kernel(
    const float* __restrict__ h, const int* __restrict__ row_ptr,
    const int* __restrict__ col, const float* __restrict__ W,
    const float* __restrict__ bias, float* __restrict__ out,
    int N, int do_relu)
{
    __shared__ float Wlds[D * D];
    {
        const float4* W4 = (const float4*)W;
        float4* Wl4 = (float4*)Wlds;
        #pragma unroll
        for (int t = 0; t < 4; ++t)
            Wl4[t * 256 + threadIdx.x] = W4[t * 256 + threadIdx.x];
    }
    __syncthreads();

    const int lane = threadIdx.x & 63;
    const int sub  = lane >> 4;       // edge subgroup 0..3
    const int fq   = lane & 15;       // feature quad (features 4*fq..4*fq+3)
    const int w    = threadIdx.x >> 6;
    const float bj = bias[lane];

    const float4* __restrict__ h4 = (const float4*)h;   // row i = h4[i*16 + fq]

    const int nwaves = gridDim.x * 4;
    for (int i0 = blockIdx.x * 4 + w; i0 < N; i0 += nwaves) {
        const int i   = __builtin_amdgcn_readfirstlane(i0);
        const int rs  = __builtin_amdgcn_readfirstlane(row_ptr[i]);
        const int re  = __builtin_amdgcn_readfirstlane(row_ptr[i + 1]);
        const int deg = re - rs;

        float4 a0 = {0,0,0,0}, a1 = {0,0,0,0}, a2 = {0,0,0,0}, a3 = {0,0,0,0};
        int last_iv = 0;

        for (int e0 = rs; e0 < re; e0 += 64) {
            int ee = e0 + lane;
            int idxv = col[(ee < re) ? ee : (re - 1)];   // 64 indices, coalesced
            last_iv = idxv;
            int rem = re - e0;                            // scalar
            int steps = (((rem < 64) ? rem : 64) + 3) >> 2;  // scalar 1..16
            int t = 0;
            for (; t + 4 <= steps; t += 4) {
                int base = (t << 2) + sub;
                int s0 = __shfl(idxv, base);
                int s1 = __shfl(idxv, base + 4);
                int s2 = __shfl(idxv, base + 8);
                int s3 = __shfl(idxv, base + 12);
                float4 v0 = h4[(size_t)s0 * 16 + fq];
                float4 v1 = h4[(size_t)s1 * 16 + fq];
                float4 v2 = h4[(size_t)s2 * 16 + fq];
                float4 v3 = h4[(size_t)s3 * 16 + fq];
                a0.x += v0.x; a0.y += v0.y; a0.z += v0.z; a0.w += v0.w;
                a1.x += v1.x; a1.y += v1.y; a1.z += v1.z; a1.w += v1.w;
                a2.x += v2.x; a2.y += v2.y; a2.z += v2.z; a2.w += v2.w;
                a3.x += v3.x; a3.y += v3.y; a3.z += v3.z; a3.w += v3.w;
            }
            for (; t < steps; ++t) {
                int s0 = __shfl(idxv, (t << 2) + sub);
                float4 v0 = h4[(size_t)s0 * 16 + fq];
                a0.x += v0.x; a0.y += v0.y; a0.z += v0.z; a0.w += v0.w;
            }
        }

        // combine step accumulators
        float4 tt;
        tt.x = (a0.x + a1.x) + (a2.x + a3.x);
        tt.y = (a0.y + a1.y) + (a2.y + a3.y);
        tt.z = (a0.z + a1.z) + (a2.z + a3.z);
        tt.w = (a0.w + a1.w) + (a2.w + a3.w);
        // reduce across the 4 edge subgroups (lanes l, l^16, l^32, l^48)
        tt.x += __shfl_xor(tt.x, 16); tt.x += __shfl_xor(tt.x, 32);
        tt.y += __shfl_xor(tt.y, 16); tt.y += __shfl_xor(tt.y, 32);
        tt.z += __shfl_xor(tt.z, 16); tt.z += __shfl_xor(tt.z, 32);
        tt.w += __shfl_xor(tt.w, 16); tt.w += __shfl_xor(tt.w, 32);

        // pad correction: clamped lanes duplicated col[re-1] `pad` times.
        // pad>0 => deg%4!=0 => last chunk had rem<64 => its lane 63 was clamped
        // to re-1, so last_iv lane 63 holds col[re-1]: shfl, no reload.
        int pad = (-deg) & 3;
        if (deg > 0 && pad) {
            int last = __shfl(last_iv, 63);
            float4 vl = h4[(size_t)last * 16 + fq];
            float fp = (float)pad;
            tt.x = fmaf(-fp, vl.x, tt.x);
            tt.y = fmaf(-fp, vl.y, tt.y);
            tt.z = fmaf(-fp, vl.z, tt.z);
            tt.w = fmaf(-fp, vl.w, tt.w);
        }

        // self term + normalize
        float4 hs = h4[(size_t)i * 16 + fq];
        float invd = 1.0f / (float)(deg + 1);
        tt.x = (tt.x + hs.x) * invd;
        tt.y = (tt.y + hs.y) * invd;
        tt.z = (tt.z + hs.z) * invd;
        tt.w = (tt.w + hs.w) * invd;

        // GEMM: o[lane] = bj + sum_k t[k] * W[k][lane]; W from LDS.
        // Bank: (k*64+lane)%32 = lane%32 -> 2-way across the wave = free.
        float o0 = bj, o1 = 0.0f, o2 = 0.0f, o3 = 0.0f;
        #pragma unroll
        for (int k = 0; k < D; k += 4) {
            const int q = k >> 2;   // source lane holding features k..k+3
            int t0 = __builtin_amdgcn_readlane(__float_as_int(tt.x), q);
            int t1 = __builtin_amdgcn_readlane(__float_as_int(tt.y), q);
            int t2 = __builtin_amdgcn_readlane(__float_as_int(tt.z), q);
            int t3 = __builtin_amdgcn_readlane(__float_as_int(tt.w), q);
            o0 = fmaf(__int_as_float(t0), Wlds[(k + 0) * D + lane], o0);
            o1 = fmaf(__int_as_float(t1), Wlds[(k + 1) * D + lane], o1);
            o2 = fmaf(__int_as_float(t2), Wlds[(k + 2) * D + lane], o2);
            o3 = fmaf(__int_as_float(t3), Wlds[(k + 3) * D + lane], o3);
        }
        float o = (o0 + o1) + (o2 + o3);
        if (do_relu) o = fmaxf(o, 0.0f);
        out[(size_t)i * D + lane] = o;
    }
}

extern "C" void kernel_launch(void* const* d_in, const int* in_sizes, int n_in,
                              void* d_out, int out_size, void* d_ws, size_t ws_size,
                              hipStream_t stream) {
    const float* x   = (const float*)d_in[0];
    const int*   src = (const int*)d_in[1];
    const int*   dst = (const int*)d_in[2];
    const float* W0  = (const float*)d_in[3];
    const float* b0  = (const float*)d_in[4];
    const float* W1  = (const float*)d_in[5];
    const float* b1  = (const float*)d_in[6];
    const float* W2  = (const float*)d_in[7];
    const float* b2  = (const float*)d_in[8];
    float* out = (float*)d_out;

    const int N = in_sizes[0] / D;   // 50000
    const int E = in_sizes[1];       // 800000

    const int scan_blocks = (N + 255) / 256;  // 196 (<= 256 required by scan_b)

    // workspace: deg | row_ptr | cursor | blocksums | col | h1 | h2
    char* ws = (char*)d_ws;
    size_t off = 0;
    auto alloc = [&](size_t bytes) -> void* {
        void* p = ws + off;
        off = (off + bytes + 255) & ~(size_t)255;
        return p;
    };
    int*   deg       = (int*)  alloc((size_t)N * sizeof(int));
    int*   row_ptr   = (int*)  alloc((size_t)(N + 1) * sizeof(int));
    int*   cursor    = (int*)  alloc((size_t)N * sizeof(int));
    int*   blocksums = (int*)  alloc((size_t)scan_blocks * sizeof(int));
    int*   col       = (int*)  alloc((size_t)E * sizeof(int));
    float* h1        = (float*)alloc((size_t)N * D * sizeof(float));
    float* h2        = (float*)alloc((size_t)N * D * sizeof(float));

    // --- build CSR (once per call; reused by all 3 layers) ---
    hipMemsetAsync(deg, 0, (size_t)N * sizeof(int), stream);
    const int e4_blocks = (E / 4 + 255) / 256;  // 782
    count_deg_kernel<<<e4_blocks, 256, 0, stream>>>(dst, deg, E);
    scan_a_kernel<<<scan_blocks, 256, 0, stream>>>(deg, row_ptr, blocksums, N);
    scan_b_kernel<<<1, 256, 0, stream>>>(blocksums, row_ptr, scan_blocks, N);
    scan_c_kernel<<<scan_blocks, 256, 0, stream>>>(row_ptr, cursor, blocksums, N);
    const int slice_size = (N + 7) / 8;         // 6250
    fill_csr_sliced_kernel<<<e4_blocks * 8, 256, 0, stream>>>(src, dst, cursor, col, E, slice_size);

    const int layer_blocks = 4096;

    sage_layer_kernel<<<layer_blocks, 256, 0, stream>>>(x,  row_ptr, col, W0, b0, h1,  N, 1);
    sage_layer_kernel<<<layer_blocks, 256, 0, stream>>>(h1, row_ptr, col, W1, b1, h2,  N, 1);
    sage_layer_kernel<<<layer_blocks, 256, 0, stream>>>(h2, row_ptr, col, W2, b2, out, N, 0);
}

// Round 7
// 284.054 us; speedup vs baseline: 1.5568x; 1.5568x over previous
//
#include <hip/hip_runtime.h>
#include <hip/hip_fp16.h>

#define D 64

struct alignas(8) half4v { __half2 a, b; };   // 4 fp16 features (8B)

// --- degree histogram over dst (4 edges/thread, int4 loads) ----------------
__global__ void count_deg_kernel(const int* __restrict__ dst, int* __restrict__ deg, int nE) {
    int e4 = (blockIdx.x * blockDim.x + threadIdx.x) * 4;
    if (e4 + 3 < nE) {
        int4 d = *(const int4*)(dst + e4);
        atomicAdd(&deg[d.x], 1);
        atomicAdd(&deg[d.y], 1);
        atomicAdd(&deg[d.z], 1);
        atomicAdd(&deg[d.w], 1);
    } else {
        for (int e = e4; e < nE; ++e) atomicAdd(&deg[dst[e]], 1);
    }
}

// --- hierarchical exclusive scan: A (per-block tile scan) ------------------
__global__ __launch_bounds__(256) void scan_a_kernel(const int* __restrict__ deg,
                                                     int* __restrict__ row_ptr,
                                                     int* __restrict__ blocksums, int N) {
    __shared__ int s[256];
    int t = threadIdx.x;
    int i = blockIdx.x * 256 + t;
    int v = (i < N) ? deg[i] : 0;
    s[t] = v;
    __syncthreads();
    #pragma unroll
    for (int d = 1; d < 256; d <<= 1) {
        int u = (t >= d) ? s[t - d] : 0;
        __syncthreads();
        s[t] += u;
        __syncthreads();
    }
    if (i < N) row_ptr[i] = s[t] - v;             // exclusive (block-local)
    if (t == 255) blocksums[blockIdx.x] = s[255]; // block total
}

// --- B: single-block exclusive scan of block sums (nb <= 256) --------------
__global__ __launch_bounds__(256) void scan_b_kernel(int* __restrict__ blocksums,
                                                     int* __restrict__ row_ptr,
                                                     int nb, int N) {
    __shared__ int s[256];
    int t = threadIdx.x;
    int v = (t < nb) ? blocksums[t] : 0;
    s[t] = v;
    __syncthreads();
    #pragma unroll
    for (int d = 1; d < 256; d <<= 1) {
        int u = (t >= d) ? s[t - d] : 0;
        __syncthreads();
        s[t] += u;
        __syncthreads();
    }
    if (t < nb) blocksums[t] = s[t] - v;  // exclusive block offsets
    if (t == 255) row_ptr[N] = s[255];    // total = E
}

// --- C: apply block offsets, emit final row_ptr + cursor -------------------
__global__ __launch_bounds__(256) void scan_c_kernel(int* __restrict__ row_ptr,
                                                     int* __restrict__ cursor,
                                                     const int* __restrict__ blocksums, int N) {
    int i = blockIdx.x * 256 + threadIdx.x;
    if (i < N) {
        int r = row_ptr[i] + blocksums[blockIdx.x];
        row_ptr[i] = r;
        cursor[i] = r;
    }
}

// --- bucket edges by dst: col[pos] = src, dst-sliced for XCD locality ------
__global__ __launch_bounds__(256) void fill_csr_sliced_kernel(
    const int* __restrict__ src, const int* __restrict__ dst,
    int* __restrict__ cursor, int* __restrict__ col,
    int nE, int slice_size)
{
    const int g  = blockIdx.x & 7;    // slice id == XCD id (perf heuristic)
    const int gb = blockIdx.x >> 3;   // block index within group
    const int lo = g * slice_size;
    const int hi = lo + slice_size;
    int e4 = (gb * 256 + (int)threadIdx.x) * 4;
    if (e4 + 3 < nE) {
        int4 d = *(const int4*)(dst + e4);
        bool m0 = (d.x >= lo) & (d.x < hi);
        bool m1 = (d.y >= lo) & (d.y < hi);
        bool m2 = (d.z >= lo) & (d.z < hi);
        bool m3 = (d.w >= lo) & (d.w < hi);
        if (m0 | m1 | m2 | m3) {
            int4 s = *(const int4*)(src + e4);
            if (m0) col[atomicAdd(&cursor[d.x], 1)] = s.x;
            if (m1) col[atomicAdd(&cursor[d.y], 1)] = s.y;
            if (m2) col[atomicAdd(&cursor[d.z], 1)] = s.z;
            if (m3) col[atomicAdd(&cursor[d.w], 1)] = s.w;
        }
    } else if (e4 < nE) {
        for (int e = e4; e < nE; ++e) {
            int dd = dst[e];
            if (dd >= lo && dd < hi) col[atomicAdd(&cursor[dd], 1)] = src[e];
        }
    }
}

// --- fused layer: out = relu?( ((sum_{s in N(i)} h[s] + h[i]) / (deg+1)) @ W + b )
// One wave per node, zero barriers in the node loop. Body = round-4 codegen
// regime (proven clean: bounds(256,4), no lambdas, zero scratch).
//
// ROUND 7: halve the gather bytes via fp16 intermediate activations.
// Evidence chain: r4 = 95MB L2-miss bytes @ 2.1 TB/s; r6's additivity test
// (1.75x occupancy + spill traffic = exactly r4-time + spill-at-stream-rate)
// proves the gather service path was ALREADY saturated at 16 waves/CU.
// Occupancy is not the lever; miss bytes are. h1/h2 in fp16: per-edge row
// 256B -> 128B (demand 205 -> 102MB), footprint 12.8 -> 6.4MB vs 32MB
// aggregate L2 (hit 60% -> ~80% expected). Accumulate + MLP stay fp32;
// x stays fp32 (layer 1 unchanged, conservative precision budget).
// IN_H: gather loads are 8B/lane half4v (2 lines/row; also halves TA
// line lookups); raw loads batched BEFORE cvt to keep 4 loads in flight.
template<bool IN_H, bool OUT_H>
__global__ __launch_bounds__(256, 4) void sage_layer_kernel(
    const void* __restrict__ hin, const int* __restrict__ row_ptr,
    const int* __restrict__ col, const float* __restrict__ W,
    const float* __restrict__ bias, void* __restrict__ hout,
    int N, int do_relu)
{
    __shared__ float Wlds[D * D];
    {
        const float4* W4 = (const float4*)W;
        float4* Wl4 = (float4*)Wlds;
        #pragma unroll
        for (int t = 0; t < 4; ++t)
            Wl4[t * 256 + threadIdx.x] = W4[t * 256 + threadIdx.x];
    }
    __syncthreads();

    const int lane = threadIdx.x & 63;
    const int sub  = lane >> 4;       // edge subgroup 0..3
    const int fq   = lane & 15;       // feature quad (features 4*fq..4*fq+3)
    const int w    = threadIdx.x >> 6;
    const float bj = bias[lane];

    const float4*  __restrict__ hp4 = (const float4*)hin;   // fp32 rows
    const half4v* __restrict__ hph = (const half4v*)hin;    // fp16 rows

    const int nwaves = gridDim.x * 4;
    for (int i0 = blockIdx.x * 4 + w; i0 < N; i0 += nwaves) {
        const int i   = __builtin_amdgcn_readfirstlane(i0);
        const int rs  = __builtin_amdgcn_readfirstlane(row_ptr[i]);
        const int re  = __builtin_amdgcn_readfirstlane(row_ptr[i + 1]);
        const int deg = re - rs;

        float4 a0 = {0,0,0,0}, a1 = {0,0,0,0}, a2 = {0,0,0,0}, a3 = {0,0,0,0};
        int last_iv = 0;

        for (int e0 = rs; e0 < re; e0 += 64) {
            int ee = e0 + lane;
            int idxv = col[(ee < re) ? ee : (re - 1)];   // 64 indices, coalesced
            last_iv = idxv;
            int rem = re - e0;                            // scalar
            int steps = (((rem < 64) ? rem : 64) + 3) >> 2;  // scalar 1..16
            int t = 0;
            for (; t + 4 <= steps; t += 4) {
                int base = (t << 2) + sub;
                int s0 = __shfl(idxv, base);
                int s1 = __shfl(idxv, base + 4);
                int s2 = __shfl(idxv, base + 8);
                int s3 = __shfl(idxv, base + 12);
                if constexpr (IN_H) {
                    // issue all 4 raw loads before any cvt (keep MLP=4)
                    half4v r0 = hph[(size_t)s0 * 16 + fq];
                    half4v r1 = hph[(size_t)s1 * 16 + fq];
                    half4v r2 = hph[(size_t)s2 * 16 + fq];
                    half4v r3 = hph[(size_t)s3 * 16 + fq];
                    float2 f;
                    f = __half22float2(r0.a); a0.x += f.x; a0.y += f.y;
                    f = __half22float2(r0.b); a0.z += f.x; a0.w += f.y;
                    f = __half22float2(r1.a); a1.x += f.x; a1.y += f.y;
                    f = __half22float2(r1.b); a1.z += f.x; a1.w += f.y;
                    f = __half22float2(r2.a); a2.x += f.x; a2.y += f.y;
                    f = __half22float2(r2.b); a2.z += f.x; a2.w += f.y;
                    f = __half22float2(r3.a); a3.x += f.x; a3.y += f.y;
                    f = __half22float2(r3.b); a3.z += f.x; a3.w += f.y;
                } else {
                    float4 v0 = hp4[(size_t)s0 * 16 + fq];
                    float4 v1 = hp4[(size_t)s1 * 16 + fq];
                    float4 v2 = hp4[(size_t)s2 * 16 + fq];
                    float4 v3 = hp4[(size_t)s3 * 16 + fq];
                    a0.x += v0.x; a0.y += v0.y; a0.z += v0.z; a0.w += v0.w;
                    a1.x += v1.x; a1.y += v1.y; a1.z += v1.z; a1.w += v1.w;
                    a2.x += v2.x; a2.y += v2.y; a2.z += v2.z; a2.w += v2.w;
                    a3.x += v3.x; a3.y += v3.y; a3.z += v3.z; a3.w += v3.w;
                }
            }
            for (; t < steps; ++t) {
                int s0 = __shfl(idxv, (t << 2) + sub);
                if constexpr (IN_H) {
                    half4v r0 = hph[(size_t)s0 * 16 + fq];
                    float2 f;
                    f = __half22float2(r0.a); a0.x += f.x; a0.y += f.y;
                    f = __half22float2(r0.b); a0.z += f.x; a0.w += f.y;
                } else {
                    float4 v0 = hp4[(size_t)s0 * 16 + fq];
                    a0.x += v0.x; a0.y += v0.y; a0.z += v0.z; a0.w += v0.w;
                }
            }
        }

        // combine step accumulators
        float4 tt;
        tt.x = (a0.x + a1.x) + (a2.x + a3.x);
        tt.y = (a0.y + a1.y) + (a2.y + a3.y);
        tt.z = (a0.z + a1.z) + (a2.z + a3.z);
        tt.w = (a0.w + a1.w) + (a2.w + a3.w);
        // reduce across the 4 edge subgroups (lanes l, l^16, l^32, l^48)
        tt.x += __shfl_xor(tt.x, 16); tt.x += __shfl_xor(tt.x, 32);
        tt.y += __shfl_xor(tt.y, 16); tt.y += __shfl_xor(tt.y, 32);
        tt.z += __shfl_xor(tt.z, 16); tt.z += __shfl_xor(tt.z, 32);
        tt.w += __shfl_xor(tt.w, 16); tt.w += __shfl_xor(tt.w, 32);

        // pad correction: clamped lanes duplicated col[re-1] `pad` times.
        // pad>0 => deg%4!=0 => last chunk had rem<64 => its lane 63 was clamped
        // to re-1, so last_iv lane 63 holds col[re-1]: shfl, no reload.
        int pad = (-deg) & 3;
        if (deg > 0 && pad) {
            int last = __shfl(last_iv, 63);
            float4 vl;
            if constexpr (IN_H) {
                half4v rl = hph[(size_t)last * 16 + fq];
                float2 f0 = __half22float2(rl.a);
                float2 f1 = __half22float2(rl.b);
                vl = make_float4(f0.x, f0.y, f1.x, f1.y);
            } else {
                vl = hp4[(size_t)last * 16 + fq];
            }
            float fp = (float)pad;
            tt.x = fmaf(-fp, vl.x, tt.x);
            tt.y = fmaf(-fp, vl.y, tt.y);
            tt.z = fmaf(-fp, vl.z, tt.z);
            tt.w = fmaf(-fp, vl.w, tt.w);
        }

        // self term + normalize
        float4 hs;
        if constexpr (IN_H) {
            half4v rs4 = hph[(size_t)i * 16 + fq];
            float2 f0 = __half22float2(rs4.a);
            float2 f1 = __half22float2(rs4.b);
            hs = make_float4(f0.x, f0.y, f1.x, f1.y);
        } else {
            hs = hp4[(size_t)i * 16 + fq];
        }
        float invd = 1.0f / (float)(deg + 1);
        tt.x = (tt.x + hs.x) * invd;
        tt.y = (tt.y + hs.y) * invd;
        tt.z = (tt.z + hs.z) * invd;
        tt.w = (tt.w + hs.w) * invd;

        // GEMM: o[lane] = bj + sum_k t[k] * W[k][lane]; W from LDS.
        // Bank: (k*64+lane)%32 = lane%32 -> 2-way across the wave = free.
        float o0 = bj, o1 = 0.0f, o2 = 0.0f, o3 = 0.0f;
        #pragma unroll
        for (int k = 0; k < D; k += 4) {
            const int q = k >> 2;   // source lane holding features k..k+3
            int t0 = __builtin_amdgcn_readlane(__float_as_int(tt.x), q);
            int t1 = __builtin_amdgcn_readlane(__float_as_int(tt.y), q);
            int t2 = __builtin_amdgcn_readlane(__float_as_int(tt.z), q);
            int t3 = __builtin_amdgcn_readlane(__float_as_int(tt.w), q);
            o0 = fmaf(__int_as_float(t0), Wlds[(k + 0) * D + lane], o0);
            o1 = fmaf(__int_as_float(t1), Wlds[(k + 1) * D + lane], o1);
            o2 = fmaf(__int_as_float(t2), Wlds[(k + 2) * D + lane], o2);
            o3 = fmaf(__int_as_float(t3), Wlds[(k + 3) * D + lane], o3);
        }
        float o = (o0 + o1) + (o2 + o3);
        if (do_relu) o = fmaxf(o, 0.0f);
        if constexpr (OUT_H) {
            ((__half*)hout)[(size_t)i * D + lane] = __float2half(o);
        } else {
            ((float*)hout)[(size_t)i * D + lane] = o;
        }
    }
}

extern "C" void kernel_launch(void* const* d_in, const int* in_sizes, int n_in,
                              void* d_out, int out_size, void* d_ws, size_t ws_size,
                              hipStream_t stream) {
    const float* x   = (const float*)d_in[0];
    const int*   src = (const int*)d_in[1];
    const int*   dst = (const int*)d_in[2];
    const float* W0  = (const float*)d_in[3];
    const float* b0  = (const float*)d_in[4];
    const float* W1  = (const float*)d_in[5];
    const float* b1  = (const float*)d_in[6];
    const float* W2  = (const float*)d_in[7];
    const float* b2  = (const float*)d_in[8];
    float* out = (float*)d_out;

    const int N = in_sizes[0] / D;   // 50000
    const int E = in_sizes[1];       // 800000

    const int scan_blocks = (N + 255) / 256;  // 196 (<= 256 required by scan_b)

    // workspace: deg | row_ptr | cursor | blocksums | col | h1h(fp16) | h2h(fp16)
    char* ws = (char*)d_ws;
    size_t off = 0;
    auto alloc = [&](size_t bytes) -> void* {
        void* p = ws + off;
        off = (off + bytes + 255) & ~(size_t)255;
        return p;
    };
    int*    deg       = (int*)   alloc((size_t)N * sizeof(int));
    int*    row_ptr   = (int*)   alloc((size_t)(N + 1) * sizeof(int));
    int*    cursor    = (int*)   alloc((size_t)N * sizeof(int));
    int*    blocksums = (int*)   alloc((size_t)scan_blocks * sizeof(int));
    int*    col       = (int*)   alloc((size_t)E * sizeof(int));
    __half* h1h       = (__half*)alloc((size_t)N * D * sizeof(__half));
    __half* h2h       = (__half*)alloc((size_t)N * D * sizeof(__half));

    // --- build CSR (once per call; reused by all 3 layers) ---
    hipMemsetAsync(deg, 0, (size_t)N * sizeof(int), stream);
    const int e4_blocks = (E / 4 + 255) / 256;  // 782
    count_deg_kernel<<<e4_blocks, 256, 0, stream>>>(dst, deg, E);
    scan_a_kernel<<<scan_blocks, 256, 0, stream>>>(deg, row_ptr, blocksums, N);
    scan_b_kernel<<<1, 256, 0, stream>>>(blocksums, row_ptr, scan_blocks, N);
    scan_c_kernel<<<scan_blocks, 256, 0, stream>>>(row_ptr, cursor, blocksums, N);
    const int slice_size = (N + 7) / 8;         // 6250
    fill_csr_sliced_kernel<<<e4_blocks * 8, 256, 0, stream>>>(src, dst, cursor, col, E, slice_size);

    const int layer_blocks = 4096;

    // L1: fp32 x -> fp16 h1 | L2: fp16 -> fp16 | L3: fp16 -> fp32 out
    sage_layer_kernel<false, true ><<<layer_blocks, 256, 0, stream>>>(x,   row_ptr, col, W0, b0, h1h, N, 1);
    sage_layer_kernel<true,  true ><<<layer_blocks, 256, 0, stream>>>(h1h, row_ptr, col, W1, b1, h2h, N, 1);
    sage_layer_kernel<true,  false><<<layer_blocks, 256, 0, stream>>>(h2h, row_ptr, col, W2, b2, out, N, 0);
}